// Round 1
// baseline (452.075 us; speedup 1.0000x reference)
//
#include <hip/hip_runtime.h>
#include <math.h>

#define BB 64
#define TT 512
#define DD 256
#define CC 20
#define LN_EPS 1e-5f

__device__ __forceinline__ float wave_reduce_sum(float v) {
  #pragma unroll
  for (int off = 32; off > 0; off >>= 1) v += __shfl_xor(v, off, 64);
  return v;
}
__device__ __forceinline__ float wave_reduce_max(float v) {
  #pragma unroll
  for (int off = 32; off > 0; off >>= 1) v = fmaxf(v, __shfl_xor(v, off, 64));
  return v;
}

// Kernel 1: emb gather + LayerNorm + (D x C) linear + log_softmax.
// One wave (64 lanes) per token, 4 tokens per 256-thread block.
// W staged in LDS transposed to c-major so each lane does a conflict-free
// float4 read per output class.
__global__ __launch_bounds__(256) void token_logits_kernel(
    const int* __restrict__ words, const float* __restrict__ emb,
    const float* __restrict__ ln_g, const float* __restrict__ ln_b,
    const float* __restrict__ W, const float* __restrict__ bias,
    float* __restrict__ logits)
{
  __shared__ __align__(16) float sW[CC * DD];  // sW[c*DD + d]
  __shared__ float sb[CC];
  int tid = threadIdx.x;
  for (int e = tid; e < CC * DD; e += 256) {
    int d = e / CC, c = e - d * CC;  // W is (D, C) d-major
    sW[c * DD + d] = W[e];
  }
  if (tid < CC) sb[tid] = bias[tid];
  __syncthreads();

  int wave = tid >> 6, lane = tid & 63;
  int token = blockIdx.x * 4 + wave;  // grid = B*T/4, always in range

  int word = words[token];
  const float4* row = (const float4*)(emb + (size_t)word * DD);
  float4 x = row[lane];
  float4 g = ((const float4*)ln_g)[lane];
  float4 be = ((const float4*)ln_b)[lane];

  float s1 = x.x + x.y + x.z + x.w;
  float s2 = x.x * x.x + x.y * x.y + x.z * x.z + x.w * x.w;
  s1 = wave_reduce_sum(s1);
  s2 = wave_reduce_sum(s2);
  float mu = s1 * (1.0f / DD);
  float var = s2 * (1.0f / DD) - mu * mu;
  float r = rsqrtf(var + LN_EPS);
  float xn0 = (x.x - mu) * r * g.x + be.x;
  float xn1 = (x.y - mu) * r * g.y + be.y;
  float xn2 = (x.z - mu) * r * g.z + be.z;
  float xn3 = (x.w - mu) * r * g.w + be.w;

  float feats[CC];
  const float4* sW4 = (const float4*)sW;
  #pragma unroll
  for (int c = 0; c < CC; ++c) {
    float4 w = sW4[c * (DD / 4) + lane];
    float p = xn0 * w.x + xn1 * w.y + xn2 * w.z + xn3 * w.w;
    p = wave_reduce_sum(p);
    feats[c] = p + sb[c];
  }

  float m = feats[0];
  #pragma unroll
  for (int c = 1; c < CC; ++c) m = fmaxf(m, feats[c]);
  float s = 0.f;
  #pragma unroll
  for (int c = 0; c < CC; ++c) s += __expf(feats[c] - m);
  float lsm = m + __logf(s);

  if (lane < CC) logits[(size_t)token * CC + lane] = feats[lane] - lsm;
}

// Kernel 2: CRF forward scan + gold score per batch element.
// One wave per batch element. Lane j (< C) owns alpha[j] and trans[:, j].
// The t-loop is the serial critical path of the whole problem.
__global__ __launch_bounds__(64) void crf_kernel(
    const float* __restrict__ logits, const int* __restrict__ seq_len,
    const int* __restrict__ target, const float* __restrict__ trans,
    const float* __restrict__ start, const float* __restrict__ end,
    float* __restrict__ nll)
{
  int b = blockIdx.x;
  int j = threadIdx.x;
  bool act = j < CC;
  int jj = act ? j : 0;  // lanes >= C shadow lane 0 (results ignored)
  int len = seq_len[b];
  const float* lb = logits + (size_t)b * TT * CC;

  float tc[CC];  // trans column j in registers
  #pragma unroll
  for (int i = 0; i < CC; ++i) tc[i] = trans[i * CC + jj];

  float alpha = lb[jj] + start[jj];

  for (int t = 1; t < len; ++t) {
    float emit = lb[t * CC + jj];  // issued early; compiler hoists above math
    float sc[CC];
    #pragma unroll
    for (int i = 0; i < CC; ++i) sc[i] = __shfl(alpha, i, 64) + tc[i];
    float m = sc[0];
    #pragma unroll
    for (int i = 1; i < CC; ++i) m = fmaxf(m, sc[i]);
    float s = 0.f;
    #pragma unroll
    for (int i = 0; i < CC; ++i) s += __expf(sc[i] - m);
    alpha = m + __logf(s) + emit;
  }

  // normalizer = logsumexp_j(alpha_j + end_j)
  float val = act ? (alpha + end[j]) : -INFINITY;
  float m = wave_reduce_max(val);
  float s = act ? __expf(val - m) : 0.f;
  s = wave_reduce_sum(s);
  float norm = m + __logf(s);

  // gold score: emit path + transition path, lanes parallel over t
  const int* tg = target + b * TT;
  float gsum = 0.f;
  for (int t = j; t < len; t += 64) {
    int cur = tg[t];
    gsum += lb[t * CC + cur];
    if (t >= 1) gsum += trans[tg[t - 1] * CC + cur];
  }
  gsum = wave_reduce_sum(gsum);

  if (j == 0) {
    gsum += start[tg[0]] + end[tg[len - 1]];
    nll[b] = norm - gsum;
  }
}

// Kernel 3: mean over B=64 nll values -> scalar output.
__global__ __launch_bounds__(64) void mean_kernel(
    const float* __restrict__ nll, float* __restrict__ out)
{
  float v = nll[threadIdx.x];
  v = wave_reduce_sum(v);
  if (threadIdx.x == 0) out[0] = v * (1.0f / BB);
}

extern "C" void kernel_launch(void* const* d_in, const int* in_sizes, int n_in,
                              void* d_out, int out_size, void* d_ws, size_t ws_size,
                              hipStream_t stream) {
  const int*   words   = (const int*)d_in[0];
  const int*   seq_len = (const int*)d_in[1];
  const int*   target  = (const int*)d_in[2];
  const float* emb     = (const float*)d_in[3];
  const float* ln_g    = (const float*)d_in[4];
  const float* ln_b    = (const float*)d_in[5];
  const float* W       = (const float*)d_in[6];
  const float* bias    = (const float*)d_in[7];
  const float* trans   = (const float*)d_in[8];
  const float* start   = (const float*)d_in[9];
  const float* endv    = (const float*)d_in[10];

  float* logits = (float*)d_ws;                     // B*T*C floats = 2.62 MB
  float* nll    = logits + (size_t)BB * TT * CC;    // B floats
  float* out    = (float*)d_out;

  token_logits_kernel<<<BB * TT / 4, 256, 0, stream>>>(words, emb, ln_g, ln_b,
                                                       W, bias, logits);
  crf_kernel<<<BB, 64, 0, stream>>>(logits, seq_len, target, trans, start,
                                    endv, nll);
  mean_kernel<<<1, 64, 0, stream>>>(nll, out);
}

// Round 2
// 337.529 us; speedup vs baseline: 1.3394x; 1.3394x over previous
//
#include <hip/hip_runtime.h>
#include <math.h>

#define BB 64
#define TT 512
#define DD 256
#define CC 20
#define LN_EPS 1e-5f

// ---- cross-lane helpers ----

// Sum across a 16-lane DPP row (all 16 lanes get the total).
__device__ __forceinline__ float dpp_sum16(float v) {
  v += __int_as_float(__builtin_amdgcn_update_dpp(0, __float_as_int(v), 0xB1, 0xF, 0xF, true));  // quad_perm [1,0,3,2]
  v += __int_as_float(__builtin_amdgcn_update_dpp(0, __float_as_int(v), 0x4E, 0xF, 0xF, true));  // quad_perm [2,3,0,1]
  v += __int_as_float(__builtin_amdgcn_update_dpp(0, __float_as_int(v), 0x141, 0xF, 0xF, true)); // row_half_mirror (xor 7 in 8)
  v += __int_as_float(__builtin_amdgcn_update_dpp(0, __float_as_int(v), 0x140, 0xF, 0xF, true)); // row_mirror (xor 15 in 16)
  return v;
}

// Sum over lanes 0..31 (values must be 0 in lanes 20..31); result valid in lanes 0..31.
__device__ __forceinline__ float sum20(float v) {
  v = dpp_sum16(v);  // row sums
  v += __int_as_float(__builtin_amdgcn_ds_swizzle(__float_as_int(v), 0x401F)); // xor16 within 32
  return v;
}

__device__ __forceinline__ float wave_reduce_sum64(float v) {
  #pragma unroll
  for (int off = 32; off > 0; off >>= 1) v += __shfl_xor(v, off, 64);
  return v;
}

// ---- Kernel 1: emb gather + LN + linear + softmax probs ----
// 16 lanes per token; block = 256 threads = 4 waves; each wave does 4 groups
// of 4 simultaneous tokens -> 64 tokens/block, grid = 512.
__global__ __launch_bounds__(256) void token_logits_kernel(
    const int* __restrict__ words, const float* __restrict__ emb,
    const float* __restrict__ ln_g, const float* __restrict__ ln_b,
    const float* __restrict__ W, const float* __restrict__ bias,
    float* __restrict__ probs)
{
  __shared__ __align__(16) float4 sW4[64 * 21];  // [d4][c], stride 21 breaks conflicts
  __shared__ float sb[CC];
  int tid = threadIdx.x;
  for (int e = tid; e < 64 * CC; e += 256) {
    int d4 = e / CC, c = e - d4 * CC;
    int base = 4 * d4 * CC + c;  // W is (D, C) row-major
    sW4[d4 * 21 + c] = make_float4(W[base], W[base + CC], W[base + 2 * CC], W[base + 3 * CC]);
  }
  if (tid < CC) sb[tid] = bias[tid];
  __syncthreads();

  int lane = tid & 63;
  int wave = tid >> 6;
  int sub = lane >> 4;   // which of 4 tokens in this wave-group
  int l = lane & 15;     // lane within token

  float4 g4[4], b4[4];
  #pragma unroll
  for (int q = 0; q < 4; ++q) {
    g4[q] = ((const float4*)ln_g)[l + 16 * q];
    b4[q] = ((const float4*)ln_b)[l + 16 * q];
  }

  for (int gidx = 0; gidx < 4; ++gidx) {
    int token = blockIdx.x * 64 + wave * 16 + gidx * 4 + sub;
    int word = words[token];
    const float4* row = (const float4*)(emb + (size_t)word * DD);
    float4 x4[4];
    #pragma unroll
    for (int q = 0; q < 4; ++q) x4[q] = row[l + 16 * q];

    float s1 = 0.f, s2 = 0.f;
    #pragma unroll
    for (int q = 0; q < 4; ++q) {
      s1 += (x4[q].x + x4[q].y) + (x4[q].z + x4[q].w);
      s2 += (x4[q].x * x4[q].x + x4[q].y * x4[q].y) + (x4[q].z * x4[q].z + x4[q].w * x4[q].w);
    }
    s1 = dpp_sum16(s1);
    s2 = dpp_sum16(s2);
    float mu = s1 * (1.f / DD);
    float var = s2 * (1.f / DD) - mu * mu;
    float r = rsqrtf(var + LN_EPS);

    float4 xn[4];
    #pragma unroll
    for (int q = 0; q < 4; ++q) {
      xn[q].x = (x4[q].x - mu) * r * g4[q].x + b4[q].x;
      xn[q].y = (x4[q].y - mu) * r * g4[q].y + b4[q].y;
      xn[q].z = (x4[q].z - mu) * r * g4[q].z + b4[q].z;
      xn[q].w = (x4[q].w - mu) * r * g4[q].w + b4[q].w;
    }

    float p[CC];
    #pragma unroll
    for (int c = 0; c < CC; ++c) p[c] = 0.f;
    #pragma unroll
    for (int q = 0; q < 4; ++q) {
      const float4* wrow = &sW4[(l + 16 * q) * 21];
      #pragma unroll
      for (int c = 0; c < CC; ++c) {
        float4 w = wrow[c];
        p[c] += (xn[q].x * w.x + xn[q].y * w.y) + (xn[q].z * w.z + xn[q].w * w.w);
      }
    }

    float feats[CC];
    #pragma unroll
    for (int c = 0; c < CC; ++c) feats[c] = dpp_sum16(p[c]) + sb[c];

    float m = feats[0];
    #pragma unroll
    for (int c = 1; c < CC; ++c) m = fmaxf(m, feats[c]);
    float e[CC];
    float ssum = 0.f;
    #pragma unroll
    for (int c = 0; c < CC; ++c) { e[c] = __expf(feats[c] - m); ssum += e[c]; }
    float inv = 1.0f / ssum;

    float* pt = probs + (size_t)token * CC;
    for (int c = l; c < CC; c += 16) pt[c] = e[c] * inv;
  }
}

// ---- Kernel 2: CRF forward scan in probability domain + gold score ----
// One wave per batch element; lane j < C owns p_j = exp(alpha_j - Z).
// Step is a pure FMA matvec: p'_j = (sum_i p_i * E_ij) * prob_tj.
// Mass per step bounded in [e^minT, e^maxT]; renorm every 32 steps.
__global__ __launch_bounds__(64) void crf_kernel(
    const float* __restrict__ probs, const int* __restrict__ seq_len,
    const int* __restrict__ target, const float* __restrict__ trans,
    const float* __restrict__ start, const float* __restrict__ end,
    float* __restrict__ nll)
{
  int b = blockIdx.x;
  int j = threadIdx.x;
  bool act = j < CC;
  int jj = act ? j : 0;
  int len = seq_len[b];
  const float* pb = probs + (size_t)b * TT * CC;

  float E[CC];
  #pragma unroll
  for (int i = 0; i < CC; ++i) {
    float tv = trans[i * CC + jj];
    E[i] = act ? __expf(tv) : 0.f;   // E=0 for idle lanes keeps their p at 0
  }

  float p = act ? pb[jj] * __expf(start[jj]) : 0.f;
  float Z = 0.f;

  for (int t = 1; t < len; ++t) {
    float pr = pb[t * CC + jj];   // independent of chain; pipelines ahead
    float q0 = 0.f, q1 = 0.f, q2 = 0.f, q3 = 0.f;
    #pragma unroll
    for (int i = 0; i < CC; i += 4) {
      q0 += __shfl(p, i + 0, 64) * E[i + 0];
      q1 += __shfl(p, i + 1, 64) * E[i + 1];
      q2 += __shfl(p, i + 2, 64) * E[i + 2];
      q3 += __shfl(p, i + 3, 64) * E[i + 3];
    }
    p = ((q0 + q1) + (q2 + q3)) * pr;
    if ((t & 31) == 0) {
      float s = sum20(p);
      Z += __logf(s);
      p *= 1.0f / s;
    }
  }

  float v = act ? p * __expf(end[jj]) : 0.f;
  float s = sum20(v);
  float norm = Z + __logf(s);

  // gold score (log domain), lanes parallel over t
  const int* tg = target + b * TT;
  float gsum = 0.f;
  for (int t = j; t < len; t += 64) {
    int cur = tg[t];
    gsum += __logf(fmaxf(pb[t * CC + cur], 1e-37f));
    if (t >= 1) gsum += trans[tg[t - 1] * CC + cur];
  }
  gsum = wave_reduce_sum64(gsum);

  if (j == 0) {
    gsum += start[tg[0]] + end[tg[len - 1]];
    nll[b] = norm - gsum;
  }
}

// ---- Kernel 3: mean over B ----
__global__ __launch_bounds__(64) void mean_kernel(
    const float* __restrict__ nll, float* __restrict__ out)
{
  float v = nll[threadIdx.x];
  v = wave_reduce_sum64(v);
  if (threadIdx.x == 0) out[0] = v * (1.0f / BB);
}

extern "C" void kernel_launch(void* const* d_in, const int* in_sizes, int n_in,
                              void* d_out, int out_size, void* d_ws, size_t ws_size,
                              hipStream_t stream) {
  const int*   words   = (const int*)d_in[0];
  const int*   seq_len = (const int*)d_in[1];
  const int*   target  = (const int*)d_in[2];
  const float* emb     = (const float*)d_in[3];
  const float* ln_g    = (const float*)d_in[4];
  const float* ln_b    = (const float*)d_in[5];
  const float* W       = (const float*)d_in[6];
  const float* bias    = (const float*)d_in[7];
  const float* trans   = (const float*)d_in[8];
  const float* start   = (const float*)d_in[9];
  const float* endv    = (const float*)d_in[10];

  float* probs = (float*)d_ws;                     // B*T*C floats = 2.62 MB
  float* nll   = probs + (size_t)BB * TT * CC;     // B floats
  float* out   = (float*)d_out;

  token_logits_kernel<<<512, 256, 0, stream>>>(words, emb, ln_g, ln_b,
                                               W, bias, probs);
  crf_kernel<<<BB, 64, 0, stream>>>(probs, seq_len, target, trans, start,
                                    endv, nll);
  mean_kernel<<<1, 64, 0, stream>>>(nll, out);
}